// Round 12
// baseline (264.932 us; speedup 1.0000x reference)
//
#include <hip/hip_runtime.h>
#include <math.h>

#define BB 4
#define CDIM 256
#define NN 2048
#define HEADS 8
#define DH 64
#define HIDDEN 512
#define THREEH 1536
#define QSCALE 0.18033688011112042f   // 0.125 * log2(e): softmax in exp2 domain

typedef __attribute__((ext_vector_type(8))) short bf16x8;
typedef __attribute__((ext_vector_type(4))) float f32x4;

static __device__ inline unsigned short f2bf(float f) {
    unsigned u = __float_as_uint(f);
    u += 0x7fff + ((u >> 16) & 1);
    return (unsigned short)(u >> 16);
}
#if __has_builtin(__builtin_amdgcn_cvt_pk_bf16_f32)
static __device__ inline unsigned pk2(float a, float b) {
    auto v = __builtin_amdgcn_cvt_pk_bf16_f32(a, b);
    return __builtin_bit_cast(unsigned, v);
}
#else
static __device__ inline unsigned pk2(float a, float b) {
    return (unsigned)f2bf(a) | ((unsigned)f2bf(b) << 16);
}
#endif
#if __has_builtin(__builtin_amdgcn_exp2f)
#define EXP2(x) __builtin_amdgcn_exp2f(x)
#else
#define EXP2(x) exp2f(x)
#endif
#define MFMA16(a, b, c) __builtin_amdgcn_mfma_f32_16x16x32_bf16(a, b, c, 0, 0, 0)
// XOR swizzle on tight 64-elem (128B) rows, 16B chunks, key=row&7: conflict-free b128 frags.
#define SWZC(row, ch) ((((ch) ^ ((row) & 7)) << 3))

// ---------------- prep_all: x transpose->bf16 (512 blocks) + weight cvt (32 blocks) ----------------
__global__ __launch_bounds__(256) void prep_all(const float* __restrict__ x,
                                                const float* __restrict__ wqkv,
                                                const float* __restrict__ wout,
                                                unsigned short* __restrict__ Xt,
                                                unsigned* __restrict__ Wqb,
                                                unsigned* __restrict__ Wob) {
    __shared__ float Ls[64][65];
    const int bx = blockIdx.x;
    if (bx < 512) {
        const int n0 = (bx & 31) * 64, c0 = ((bx >> 5) & 3) * 64, b = bx >> 7;
        const int t = threadIdx.x;
        const int r16 = t >> 4, c16 = t & 15;
#pragma unroll
        for (int s = 0; s < 4; ++s) {
            const int c = s * 16 + r16;
            float4 v = *(const float4*)&x[((size_t)(b * CDIM + c0 + c)) * NN + n0 + c16 * 4];
            *(float4*)&Ls[c][c16 * 4] = v;
        }
        __syncthreads();
#pragma unroll
        for (int s = 0; s < 4; ++s) {
            const int n = s * 16 + r16;
            const int c4 = c16 * 4;
            uint2 u;
            u.x = pk2(Ls[c4][n], Ls[c4 + 1][n]);
            u.y = pk2(Ls[c4 + 2][n], Ls[c4 + 3][n]);
            *(uint2*)&Xt[((size_t)(b * NN) + n0 + n) * CDIM + c0 + c4] = u;
        }
    } else if (bx < 536) {
        const int tt = (bx - 512) * 256 + threadIdx.x;
#pragma unroll 4
        for (int j = 0; j < 16; ++j) {
            const int i4 = tt + j * 6144;
            const int e = i4 * 4;
            const float s = ((e >> 8) < HIDDEN) ? QSCALE : 1.f;
            float4 v = *(const float4*)&wqkv[e];
            Wqb[i4 * 2 + 0] = pk2(v.x * s, v.y * s);
            Wqb[i4 * 2 + 1] = pk2(v.z * s, v.w * s);
        }
    } else {
        const int tt = (bx - 536) * 256 + threadIdx.x;
#pragma unroll 4
        for (int j = 0; j < 16; ++j) {
            const int i4 = tt + j * 2048;
            const int e = i4 * 4;
            float4 v = *(const float4*)&wout[e];
            Wob[i4 * 2 + 0] = pk2(v.x, v.y);
            Wob[i4 * 2 + 1] = pk2(v.z, v.w);
        }
    }
}

// ---------------- Kernel A: qkv projection, 128x128 LDS-tiled MFMA GEMM (r8 exact) ----------------
__global__ __launch_bounds__(256, 3) void qkv_gemm(const unsigned short* __restrict__ Xt,
                                                   const unsigned short* __restrict__ Wqb,
                                                   unsigned short* __restrict__ Qb,
                                                   unsigned short* __restrict__ Kb,
                                                   unsigned short* __restrict__ Vb) {
    __shared__ unsigned short Xs[128 * 64], Ws[128 * 64];
    const int bn0 = blockIdx.x * 128, o0 = blockIdx.y * 128;
    const int t = threadIdx.x, l = t & 63, w = t >> 6, lo = l & 15, quad = l >> 4;
    const int wo = (w >> 1) * 64, wn = (w & 1) * 64;
    const int sr = t >> 1, scb = (t & 1) * 4;
    const bool isV = (o0 >= 2 * HIDDEN);
    f32x4 acc[4][4];
#pragma unroll
    for (int i = 0; i < 4; ++i)
#pragma unroll
        for (int j = 0; j < 4; ++j) acc[i][j] = (f32x4){0.f, 0.f, 0.f, 0.f};

    for (int kc = 0; kc < CDIM; kc += 64) {
        __syncthreads();
#pragma unroll
        for (int j = 0; j < 4; ++j) {
            const int ch = scb + j;
            *(uint4*)&Xs[sr * 64 + SWZC(sr, ch)] =
                *(const uint4*)&Xt[(size_t)(bn0 + sr) * CDIM + kc + ch * 8];
            *(uint4*)&Ws[sr * 64 + SWZC(sr, ch)] =
                *(const uint4*)&Wqb[(size_t)(o0 + sr) * CDIM + kc + ch * 8];
        }
        __syncthreads();
#pragma unroll
        for (int kk = 0; kk < 2; ++kk) {
            const int swz = SWZC(lo, kk * 4 + quad);
            if (!isV) {
                bf16x8 af[4], bv[4];
#pragma unroll
                for (int ot = 0; ot < 4; ++ot) af[ot] = *(const bf16x8*)&Ws[(wo + ot * 16 + lo) * 64 + swz];
#pragma unroll
                for (int nt = 0; nt < 4; ++nt) bv[nt] = *(const bf16x8*)&Xs[(wn + nt * 16 + lo) * 64 + swz];
#pragma unroll
                for (int ot = 0; ot < 4; ++ot)
#pragma unroll
                    for (int nt = 0; nt < 4; ++nt) acc[ot][nt] = MFMA16(af[ot], bv[nt], acc[ot][nt]);
            } else {
                bf16x8 af[4], bv[4];
#pragma unroll
                for (int mt = 0; mt < 4; ++mt) af[mt] = *(const bf16x8*)&Xs[(wn + mt * 16 + lo) * 64 + swz];
#pragma unroll
                for (int ot = 0; ot < 4; ++ot) bv[ot] = *(const bf16x8*)&Ws[(wo + ot * 16 + lo) * 64 + swz];
#pragma unroll
                for (int mt = 0; mt < 4; ++mt)
#pragma unroll
                    for (int ot = 0; ot < 4; ++ot) acc[mt][ot] = MFMA16(af[mt], bv[ot], acc[mt][ot]);
            }
        }
    }
    if (!isV) {
#pragma unroll
        for (int ot = 0; ot < 4; ++ot) {
            const int og = o0 + wo + ot * 16 + quad * 4;
            const int h = (og >> 6) & 7;
            const int c0 = og & 63;
            unsigned short* dst = (og >= HIDDEN) ? Kb : Qb;
#pragma unroll
            for (int nt = 0; nt < 4; ++nt) {
                const int bn = bn0 + wn + nt * 16 + lo;
                const int b = bn >> 11, n = bn & 2047;
                uint2 u;
                u.x = pk2(acc[ot][nt][0], acc[ot][nt][1]);
                u.y = pk2(acc[ot][nt][2], acc[ot][nt][3]);
                *(uint2*)&dst[(((size_t)(b * HEADS + h)) * NN + n) * DH + c0] = u;
            }
        }
    } else {
#pragma unroll
        for (int mt = 0; mt < 4; ++mt) {
            const int bn = bn0 + wn + mt * 16 + quad * 4;
            const int b = bn >> 11, m = bn & 2047;
#pragma unroll
            for (int ot = 0; ot < 4; ++ot) {
                const int og = o0 + wo + ot * 16 + lo;
                const int h = (og >> 6) & 7;
                const int c = og & 63;
                uint2 u;
                u.x = pk2(acc[mt][ot][0], acc[mt][ot][1]);
                u.y = pk2(acc[mt][ot][2], acc[mt][ot][3]);
                *(uint2*)&Vb[(((size_t)(b * HEADS + h)) * DH + c) * NN + m] = u;
            }
        }
    }
}

// ---------------- Kernel B: flash attention, in-block m-split (2 wave-pairs) ----------------
// 256-thread blocks (the geometry that never spills). Pair p = waves {2p, 2p+1} handles
// m in [p*1024, p*1024+1024) over the block's 64 q, with its OWN 16 KB K/V LDS region.
// Max-free softmax makes partials linear: end merge = one LDS round-trip (O sum, l sum).
// 1024 blocks -> 3 blocks/CU (48 KB LDS), 12 waves/CU in 3 independent barrier groups.
__global__ __launch_bounds__(256, 3) void flash_attn(const unsigned short* __restrict__ Qb,
                                                     const unsigned short* __restrict__ Kb,
                                                     const unsigned short* __restrict__ Vb,
                                                     unsigned short* __restrict__ Yb) {
    __shared__ unsigned short Ks[2 * 64 * 64], Vs[2 * 64 * 64], Ps[128 * 64];   // 48 KB
    const int flat = blockIdx.x;                 // 1024 blocks
    const int rest = flat >> 3;
    const int bh = ((rest & 3) << 3) | (flat & 7);   // XCD-local (b,h)
    const int q0 = (rest >> 2) * 64;
    const int b = bh >> 3, h = bh & 7;
    const int t = threadIdx.x, l = t & 63, w = t >> 6, lo = l & 15, quad = l >> 4;
    const int pair = w >> 1, wp = w & 1;
    const unsigned short* Qp = Qb + (size_t)bh * NN * DH;
    const unsigned short* Kp = Kb + (size_t)bh * NN * DH;
    const unsigned short* Vp = Vb + (size_t)bh * DH * NN;
    const int qbase = q0 + 32 * wp;
    bf16x8 bQ[2][2];
#pragma unroll
    for (int qt = 0; qt < 2; ++qt)
#pragma unroll
        for (int hh = 0; hh < 2; ++hh)
            bQ[qt][hh] = *(const bf16x8*)&Qp[(size_t)(qbase + qt * 16 + lo) * DH + hh * 32 + quad * 8];
    f32x4 O[4][2], lacc[2];
#pragma unroll
    for (int i = 0; i < 4; ++i)
#pragma unroll
        for (int j = 0; j < 2; ++j) O[i][j] = (f32x4){0.f, 0.f, 0.f, 0.f};
#pragma unroll
    for (int j = 0; j < 2; ++j) lacc[j] = (f32x4){0.f, 0.f, 0.f, 0.f};
    const int tp = t & 127;                        // 128 threads per pair stage its 8+8 KB tile
    const int sr = tp >> 1, scb = (tp & 1) * 4;    // row 0..63, 4 chunks of 16B each for K and V
    const int lbase = pair * 4096;                 // pair's K/V LDS region (shorts)
    const int key = lo & 7;
    const int mstart = pair * (NN / 2), mend = mstart + NN / 2;
    bf16x8 aOnes;
    {
        const short v = (lo == 0) ? (short)0x3F80 : (short)0;   // bf16 1.0 on row 0
        aOnes = (bf16x8){v, v, v, v, v, v, v, v};
    }
    // prefetch first tile of this pair's m-range
    uint4 rk[4], rv[4];
#pragma unroll
    for (int j = 0; j < 4; ++j) {
        rk[j] = *(const uint4*)&Kp[(size_t)(mstart + sr) * DH + (scb + j) * 8];
        rv[j] = *(const uint4*)&Vp[(size_t)sr * NN + mstart + (scb + j) * 8];
    }

#pragma unroll 1
    for (int m0 = mstart; m0 < mend; m0 += 64) {
        __syncthreads();
#pragma unroll
        for (int j = 0; j < 4; ++j) {
            const int ch = scb + j;
            *(uint4*)&Ks[lbase + sr * 64 + SWZC(sr, ch)] = rk[j];
            *(uint4*)&Vs[lbase + sr * 64 + SWZC(sr, ch)] = rv[j];
        }
        __syncthreads();
        {   // prefetch next tile (clamped; last iter re-reads from L1)
            const int m1 = (m0 + 64 < mend) ? (m0 + 64) : m0;
#pragma unroll
            for (int j = 0; j < 4; ++j) {
                rk[j] = *(const uint4*)&Kp[(size_t)(m1 + sr) * DH + (scb + j) * 8];
                rv[j] = *(const uint4*)&Vp[(size_t)sr * NN + m1 + (scb + j) * 8];
            }
        }
        // ---- S^T = K·Q^T, P = exp2(S) immediately (no max, no rescale) ----
#pragma unroll
        for (int nt = 0; nt < 4; ++nt) {
            const int rb = lbase + (nt * 16 + lo) * 64;
            bf16x8 a0 = *(const bf16x8*)&Ks[rb + SWZC(lo, quad)];
            bf16x8 a1 = *(const bf16x8*)&Ks[rb + SWZC(lo, quad + 4)];
            const int pcol = (((nt * 2 + (quad >> 1)) ^ key) << 3) + (quad & 1) * 4;
#pragma unroll
            for (int qt = 0; qt < 2; ++qt) {
                f32x4 z = (f32x4){0.f, 0.f, 0.f, 0.f};
                z = MFMA16(a0, bQ[qt][0], z);
                z = MFMA16(a1, bQ[qt][1], z);
                f32x4 p;
#pragma unroll
                for (int i = 0; i < 4; ++i) p[i] = EXP2(z[i]);
                uint2 u;
                u.x = pk2(p[0], p[1]);
                u.y = pk2(p[2], p[3]);
                *(uint2*)&Ps[(32 * w + qt * 16 + lo) * 64 + pcol] = u;
            }
        }
        asm volatile("s_waitcnt lgkmcnt(0)" ::: "memory");   // wave-private P write->read
        bf16x8 pb[2][2];
#pragma unroll
        for (int qt = 0; qt < 2; ++qt) {
            const int prow = (32 * w + qt * 16 + lo) * 64;
            pb[qt][0] = *(const bf16x8*)&Ps[prow + SWZC(lo, quad)];
            pb[qt][1] = *(const bf16x8*)&Ps[prow + SWZC(lo, quad + 4)];
        }
        // ---- O^T += V^T·P^T (+ ones-row for l) ----
#pragma unroll
        for (int ct = 0; ct < 4; ++ct) {
            const int rb = lbase + (ct * 16 + lo) * 64;
            bf16x8 a0 = *(const bf16x8*)&Vs[rb + SWZC(lo, quad)];
            bf16x8 a1 = *(const bf16x8*)&Vs[rb + SWZC(lo, quad + 4)];
#pragma unroll
            for (int qt = 0; qt < 2; ++qt) {
                O[ct][qt] = MFMA16(a0, pb[qt][0], O[ct][qt]);
                O[ct][qt] = MFMA16(a1, pb[qt][1], O[ct][qt]);
            }
        }
#pragma unroll
        for (int qt = 0; qt < 2; ++qt) {
            lacc[qt] = MFMA16(aOnes, pb[qt][0], lacc[qt]);
            lacc[qt] = MFMA16(aOnes, pb[qt][1], lacc[qt]);
        }
    }

    // ---- linear merge of the two pair-partials (max-free => plain sums) ----
    __syncthreads();                               // all loop LDS reads done; Ks/Vs reusable
    float* OpF = (float*)Ks;                       // [wp][32 q][68 c] fp32 (stride-68 pad)
    float* lF  = (float*)Vs;                       // [wp][32 q]
    if (pair == 1) {
#pragma unroll
        for (int qt = 0; qt < 2; ++qt) {
#pragma unroll
            for (int ct = 0; ct < 4; ++ct)
                *(f32x4*)&OpF[wp * 2176 + (qt * 16 + lo) * 68 + ct * 16 + quad * 4] = O[ct][qt];
            if (quad == 0) lF[wp * 32 + qt * 16 + lo] = lacc[qt][0];
        }
    }
    __syncthreads();
    if (pair == 0) {
#pragma unroll
        for (int qt = 0; qt < 2; ++qt) {
            const float lv = __shfl(lacc[qt][0], lo) + lF[wp * 32 + qt * 16 + lo];
            const float inv = 1.f / lv;
            const int q = qbase + qt * 16 + lo;
            unsigned short* yrow = Yb + ((size_t)(b * NN) + q) * HIDDEN + h * DH;
#pragma unroll
            for (int ct = 0; ct < 4; ++ct) {
                f32x4 s = O[ct][qt] + *(const f32x4*)&OpF[wp * 2176 + (qt * 16 + lo) * 68 + ct * 16 + quad * 4];
                uint2 u;
                u.x = pk2(s[0] * inv, s[1] * inv);
                u.y = pk2(s[2] * inv, s[3] * inv);
                *(uint2*)&yrow[ct * 16 + quad * 4] = u;
            }
        }
    }
}

// ---------------- Kernel C: out projection, 128x64 LDS-tiled MFMA GEMM + bias (r8 exact) ----------------
__global__ __launch_bounds__(256, 4) void out_gemm(const unsigned short* __restrict__ Yb,
                                                   const unsigned short* __restrict__ Wob,
                                                   const float* __restrict__ bias,
                                                   float* __restrict__ out) {
    __shared__ unsigned short Ys[128 * 64], Wos[64 * 64];
    const int bn0 = blockIdx.x * 128, o0 = blockIdx.y * 64;
    const int t = threadIdx.x, l = t & 63, w = t >> 6, lo = l & 15, quad = l >> 4;
    const int wn = w * 32;
    const int sr = t >> 1, scb = (t & 1) * 4;
    const int sr2 = t >> 2, scb2 = (t & 3) * 2;
    f32x4 acc[2][4];
#pragma unroll
    for (int i = 0; i < 2; ++i)
#pragma unroll
        for (int j = 0; j < 4; ++j) acc[i][j] = (f32x4){0.f, 0.f, 0.f, 0.f};

    for (int kc = 0; kc < HIDDEN; kc += 64) {
        __syncthreads();
#pragma unroll
        for (int j = 0; j < 4; ++j) {
            const int ch = scb + j;
            *(uint4*)&Ys[sr * 64 + SWZC(sr, ch)] =
                *(const uint4*)&Yb[(size_t)(bn0 + sr) * HIDDEN + kc + ch * 8];
        }
#pragma unroll
        for (int j = 0; j < 2; ++j) {
            const int ch = scb2 + j;
            *(uint4*)&Wos[sr2 * 64 + SWZC(sr2, ch)] =
                *(const uint4*)&Wob[(size_t)(o0 + sr2) * HIDDEN + kc + ch * 8];
        }
        __syncthreads();
#pragma unroll
        for (int kk = 0; kk < 2; ++kk) {
            const int swz = SWZC(lo, kk * 4 + quad);
            bf16x8 bv[4];
#pragma unroll
            for (int ot = 0; ot < 4; ++ot) bv[ot] = *(const bf16x8*)&Wos[(ot * 16 + lo) * 64 + swz];
#pragma unroll
            for (int mt = 0; mt < 2; ++mt) {
                bf16x8 av = *(const bf16x8*)&Ys[(wn + mt * 16 + lo) * 64 + swz];
#pragma unroll
                for (int ot = 0; ot < 4; ++ot) acc[mt][ot] = MFMA16(av, bv[ot], acc[mt][ot]);
            }
        }
    }
#pragma unroll
    for (int mt = 0; mt < 2; ++mt) {
        const int bn = bn0 + wn + mt * 16 + quad * 4;
        const int b = bn >> 11, n = bn & 2047;
#pragma unroll
        for (int ot = 0; ot < 4; ++ot) {
            const int o = o0 + ot * 16 + lo;
            *(f32x4*)&out[((size_t)(b * CDIM + o)) * NN + n] = acc[mt][ot] + bias[o];
        }
    }
}

extern "C" void kernel_launch(void* const* d_in, const int* in_sizes, int n_in,
                              void* d_out, int out_size, void* d_ws, size_t ws_size,
                              hipStream_t stream) {
    const float* x     = (const float*)d_in[0];
    const float* w_qkv = (const float*)d_in[1];
    const float* w_out = (const float*)d_in[2];
    const float* b_out = (const float*)d_in[3];
    float* out = (float*)d_out;

    unsigned short* Wqb = (unsigned short*)d_ws;
    unsigned short* Wob = Wqb + (size_t)THREEH * CDIM;
    unsigned short* Xt  = Wob + (size_t)CDIM * HIDDEN;
    unsigned short* Qb  = Xt + (size_t)BB * NN * CDIM;
    unsigned short* Kb  = Qb + (size_t)BB * HEADS * NN * DH;
    unsigned short* Vb  = Kb + (size_t)BB * HEADS * NN * DH;
    unsigned short* Yb  = Vb + (size_t)BB * HEADS * DH * NN;

    prep_all<<<544, 256, 0, stream>>>(x, w_qkv, w_out, Xt, (unsigned*)Wqb, (unsigned*)Wob);
    qkv_gemm<<<dim3(BB * NN / 128, THREEH / 128), 256, 0, stream>>>(Xt, Wqb, Qb, Kb, Vb);
    flash_attn<<<1024, 256, 0, stream>>>(Qb, Kb, Vb, Yb);
    out_gemm<<<dim3(BB * NN / 128, CDIM / 64), 256, 0, stream>>>(Yb, Wob, b_out, out);
}

// Round 13
// 156.536 us; speedup vs baseline: 1.6925x; 1.6925x over previous
//
#include <hip/hip_runtime.h>
#include <math.h>

#define BB 4
#define CDIM 256
#define NN 2048
#define HEADS 8
#define DH 64
#define HIDDEN 512
#define THREEH 1536
#define QSCALE 0.18033688011112042f   // 0.125 * log2(e): softmax in exp2 domain

typedef __attribute__((ext_vector_type(8))) short bf16x8;
typedef __attribute__((ext_vector_type(4))) float f32x4;

static __device__ inline unsigned short f2bf(float f) {
    unsigned u = __float_as_uint(f);
    u += 0x7fff + ((u >> 16) & 1);
    return (unsigned short)(u >> 16);
}
#if __has_builtin(__builtin_amdgcn_cvt_pk_bf16_f32)
static __device__ inline unsigned pk2(float a, float b) {
    auto v = __builtin_amdgcn_cvt_pk_bf16_f32(a, b);
    return __builtin_bit_cast(unsigned, v);
}
#else
static __device__ inline unsigned pk2(float a, float b) {
    return (unsigned)f2bf(a) | ((unsigned)f2bf(b) << 16);
}
#endif
#if __has_builtin(__builtin_amdgcn_exp2f)
#define EXP2(x) __builtin_amdgcn_exp2f(x)
#else
#define EXP2(x) exp2f(x)
#endif
#define MFMA16(a, b, c) __builtin_amdgcn_mfma_f32_16x16x32_bf16(a, b, c, 0, 0, 0)
// XOR swizzle on tight 64-elem (128B) rows, 16B chunks, key=row&7: conflict-free b128 frags.
#define SWZC(row, ch) ((((ch) ^ ((row) & 7)) << 3))

// ---------------- prep_all: x transpose->bf16 (512 blocks) + weight cvt (32 blocks) ----------------
__global__ __launch_bounds__(256) void prep_all(const float* __restrict__ x,
                                                const float* __restrict__ wqkv,
                                                const float* __restrict__ wout,
                                                unsigned short* __restrict__ Xt,
                                                unsigned* __restrict__ Wqb,
                                                unsigned* __restrict__ Wob) {
    __shared__ float Ls[64][65];
    const int bx = blockIdx.x;
    if (bx < 512) {
        const int n0 = (bx & 31) * 64, c0 = ((bx >> 5) & 3) * 64, b = bx >> 7;
        const int t = threadIdx.x;
        const int r16 = t >> 4, c16 = t & 15;
#pragma unroll
        for (int s = 0; s < 4; ++s) {
            const int c = s * 16 + r16;
            float4 v = *(const float4*)&x[((size_t)(b * CDIM + c0 + c)) * NN + n0 + c16 * 4];
            *(float4*)&Ls[c][c16 * 4] = v;
        }
        __syncthreads();
#pragma unroll
        for (int s = 0; s < 4; ++s) {
            const int n = s * 16 + r16;
            const int c4 = c16 * 4;
            uint2 u;
            u.x = pk2(Ls[c4][n], Ls[c4 + 1][n]);
            u.y = pk2(Ls[c4 + 2][n], Ls[c4 + 3][n]);
            *(uint2*)&Xt[((size_t)(b * NN) + n0 + n) * CDIM + c0 + c4] = u;
        }
    } else if (bx < 536) {
        const int tt = (bx - 512) * 256 + threadIdx.x;
#pragma unroll 4
        for (int j = 0; j < 16; ++j) {
            const int i4 = tt + j * 6144;
            const int e = i4 * 4;
            const float s = ((e >> 8) < HIDDEN) ? QSCALE : 1.f;
            float4 v = *(const float4*)&wqkv[e];
            Wqb[i4 * 2 + 0] = pk2(v.x * s, v.y * s);
            Wqb[i4 * 2 + 1] = pk2(v.z * s, v.w * s);
        }
    } else {
        const int tt = (bx - 536) * 256 + threadIdx.x;
#pragma unroll 4
        for (int j = 0; j < 16; ++j) {
            const int i4 = tt + j * 2048;
            const int e = i4 * 4;
            float4 v = *(const float4*)&wout[e];
            Wob[i4 * 2 + 0] = pk2(v.x, v.y);
            Wob[i4 * 2 + 1] = pk2(v.z, v.w);
        }
    }
}

// ---------------- Kernel A: qkv projection, 128x128 tiles; LDS-bounced coalesced stores ----------------
__global__ __launch_bounds__(256, 3) void qkv_gemm(const unsigned short* __restrict__ Xt,
                                                   const unsigned short* __restrict__ Wqb,
                                                   unsigned short* __restrict__ Qb,
                                                   unsigned short* __restrict__ Kb,
                                                   unsigned short* __restrict__ Vb) {
    __shared__ unsigned short SB[16384];          // K-loop: Xs=SB[0:8192), Ws=SB[8192:); epilogue: 128x128 bounce
    unsigned short* Xs = SB;
    unsigned short* Ws = SB + 8192;
    const int bn0 = blockIdx.x * 128, o0 = blockIdx.y * 128;
    const int t = threadIdx.x, l = t & 63, w = t >> 6, lo = l & 15, quad = l >> 4;
    const int wo = (w >> 1) * 64, wn = (w & 1) * 64;
    const int sr = t >> 1, scb = (t & 1) * 4;
    const bool isV = (o0 >= 2 * HIDDEN);
    f32x4 acc[4][4];
#pragma unroll
    for (int i = 0; i < 4; ++i)
#pragma unroll
        for (int j = 0; j < 4; ++j) acc[i][j] = (f32x4){0.f, 0.f, 0.f, 0.f};

    for (int kc = 0; kc < CDIM; kc += 64) {
        __syncthreads();
#pragma unroll
        for (int j = 0; j < 4; ++j) {
            const int ch = scb + j;
            *(uint4*)&Xs[sr * 64 + SWZC(sr, ch)] =
                *(const uint4*)&Xt[(size_t)(bn0 + sr) * CDIM + kc + ch * 8];
            *(uint4*)&Ws[sr * 64 + SWZC(sr, ch)] =
                *(const uint4*)&Wqb[(size_t)(o0 + sr) * CDIM + kc + ch * 8];
        }
        __syncthreads();
#pragma unroll
        for (int kk = 0; kk < 2; ++kk) {
            const int swz = SWZC(lo, kk * 4 + quad);
            if (!isV) {
                bf16x8 af[4], bv[4];
#pragma unroll
                for (int ot = 0; ot < 4; ++ot) af[ot] = *(const bf16x8*)&Ws[(wo + ot * 16 + lo) * 64 + swz];
#pragma unroll
                for (int nt = 0; nt < 4; ++nt) bv[nt] = *(const bf16x8*)&Xs[(wn + nt * 16 + lo) * 64 + swz];
#pragma unroll
                for (int ot = 0; ot < 4; ++ot)
#pragma unroll
                    for (int nt = 0; nt < 4; ++nt) acc[ot][nt] = MFMA16(af[ot], bv[nt], acc[ot][nt]);
            } else {
                bf16x8 af[4], bv[4];
#pragma unroll
                for (int mt = 0; mt < 4; ++mt) af[mt] = *(const bf16x8*)&Xs[(wn + mt * 16 + lo) * 64 + swz];
#pragma unroll
                for (int ot = 0; ot < 4; ++ot) bv[ot] = *(const bf16x8*)&Ws[(wo + ot * 16 + lo) * 64 + swz];
#pragma unroll
                for (int mt = 0; mt < 4; ++mt)
#pragma unroll
                    for (int ot = 0; ot < 4; ++ot) acc[mt][ot] = MFMA16(af[mt], bv[ot], acc[mt][ot]);
            }
        }
    }
    // ---- epilogue: acc -> swizzled LDS bounce -> coalesced wide stores ----
    __syncthreads();                               // all waves' frag reads done before overwrite
    const int bb = bn0 >> 11, n_glob = bn0 & 2047; // 128-tile never crosses a batch boundary
    if (!isV) {
        // bounce layout L[n' 128][o' 128] bf16; 8B groups, p' = p ^ (n'&31)
#pragma unroll
        for (int ot = 0; ot < 4; ++ot) {
            const int p = (wo >> 2) + ot * 4 + quad;       // o'>>2
#pragma unroll
            for (int nt = 0; nt < 4; ++nt) {
                const int nn = wn + nt * 16 + lo;
                uint2 u;
                u.x = pk2(acc[ot][nt][0], acc[ot][nt][1]);
                u.y = pk2(acc[ot][nt][2], acc[ot][nt][3]);
                *(uint2*)&SB[nn * 128 + ((p ^ (nn & 31)) << 2)] = u;
            }
        }
        __syncthreads();
        const bool isK = (o0 >= HIDDEN);
        const int hbase = (o0 - (isK ? HIDDEN : 0)) >> 6;
        unsigned short* dst = isK ? Kb : Qb;
        const int nn = t & 127, e = t >> 7;        // row n'', head-half e
        uint2 gbuf[16];
#pragma unroll
        for (int j = 0; j < 16; ++j) {
            const int p = e * 16 + j;
            gbuf[j] = *(const uint2*)&SB[nn * 128 + ((p ^ (nn & 31)) << 2)];
        }
        unsigned short* drow = dst + (((size_t)(bb * HEADS + hbase + e)) * NN + n_glob + nn) * DH;
#pragma unroll
        for (int j = 0; j < 8; ++j) *(uint4*)&drow[j * 8] = *(uint4*)&gbuf[j * 2];
    } else {
        // bounce layout L[o' 128][m' 128] bf16; p' = p ^ (o'&31)
#pragma unroll
        for (int mt = 0; mt < 4; ++mt) {
            const int p = (wn >> 2) + mt * 4 + quad;       // m'>>2
#pragma unroll
            for (int ot = 0; ot < 4; ++ot) {
                const int oo = wo + ot * 16 + lo;
                uint2 u;
                u.x = pk2(acc[mt][ot][0], acc[mt][ot][1]);
                u.y = pk2(acc[mt][ot][2], acc[mt][ot][3]);
                *(uint2*)&SB[oo * 128 + ((p ^ (oo & 31)) << 2)] = u;
            }
        }
        __syncthreads();
        const int hbase = (o0 - 2 * HIDDEN) >> 6;
        const int oo = t >> 1, mh = t & 1;         // row o'' (=head c), m-half
        uint2 gbuf[16];
#pragma unroll
        for (int j = 0; j < 16; ++j) {
            const int p = mh * 16 + j;
            gbuf[j] = *(const uint2*)&SB[oo * 128 + ((p ^ (oo & 31)) << 2)];
        }
        const int h = hbase + (oo >> 6), c = oo & 63;
        unsigned short* drow = Vb + (((size_t)(bb * HEADS + h)) * DH + c) * NN + n_glob + mh * 64;
#pragma unroll
        for (int j = 0; j < 8; ++j) *(uint4*)&drow[j * 8] = *(uint4*)&gbuf[j * 2];
    }
}

// ---------------- Kernel B: flash attention (r8 loop exact) + LDS-bounced Y store ----------------
__global__ __launch_bounds__(256, 4) void flash_attn(const unsigned short* __restrict__ Qb,
                                                     const unsigned short* __restrict__ Kb,
                                                     const unsigned short* __restrict__ Vb,
                                                     unsigned short* __restrict__ Yb) {
    __shared__ unsigned short Ks[64 * 64], Vs[64 * 64], Ps[128 * 64];
    const int flat = blockIdx.x;                 // 512 blocks
    const int rest = flat >> 3;
    const int bh = ((rest & 3) << 3) | (flat & 7);   // XCD-local (b,h)
    const int q0 = (rest >> 2) * 128;
    const int b = bh >> 3, h = bh & 7;
    const int t = threadIdx.x, l = t & 63, w = t >> 6, lo = l & 15, quad = l >> 4;
    const unsigned short* Qp = Qb + (size_t)bh * NN * DH;
    const unsigned short* Kp = Kb + (size_t)bh * NN * DH;
    const unsigned short* Vp = Vb + (size_t)bh * DH * NN;
    const int qbase = q0 + 32 * w;
    bf16x8 bQ[2][2];
#pragma unroll
    for (int qt = 0; qt < 2; ++qt)
#pragma unroll
        for (int hh = 0; hh < 2; ++hh)
            bQ[qt][hh] = *(const bf16x8*)&Qp[(size_t)(qbase + qt * 16 + lo) * DH + hh * 32 + quad * 8];
    f32x4 O[4][2], lacc[2];
#pragma unroll
    for (int i = 0; i < 4; ++i)
#pragma unroll
        for (int j = 0; j < 2; ++j) O[i][j] = (f32x4){0.f, 0.f, 0.f, 0.f};
#pragma unroll
    for (int j = 0; j < 2; ++j) lacc[j] = (f32x4){0.f, 0.f, 0.f, 0.f};
    const int sr = t >> 3, sc = t & 7;
    const int kst0 = sr * 64 + SWZC(sr, sc);
    const int key = lo & 7;
    bf16x8 aOnes;
    {
        const short v = (lo == 0) ? (short)0x3F80 : (short)0;   // bf16 1.0 on row 0
        aOnes = (bf16x8){v, v, v, v, v, v, v, v};
    }
    // prefetch iter 0
    uint4 rk0 = *(const uint4*)&Kp[(size_t)sr * DH + sc * 8];
    uint4 rk1 = *(const uint4*)&Kp[(size_t)(sr + 32) * DH + sc * 8];
    uint4 rv0 = *(const uint4*)&Vp[(size_t)sr * NN + sc * 8];
    uint4 rv1 = *(const uint4*)&Vp[(size_t)(sr + 32) * NN + sc * 8];

#pragma unroll 1
    for (int m0 = 0; m0 < NN; m0 += 64) {
        __syncthreads();
        *(uint4*)&Ks[kst0] = rk0;
        *(uint4*)&Ks[kst0 + 2048] = rk1;
        *(uint4*)&Vs[kst0] = rv0;
        *(uint4*)&Vs[kst0 + 2048] = rv1;
        __syncthreads();
        {   // prefetch next tile (clamped; last iter re-reads from L1)
            const int m1 = (m0 + 64 < NN) ? (m0 + 64) : m0;
            rk0 = *(const uint4*)&Kp[(size_t)(m1 + sr) * DH + sc * 8];
            rk1 = *(const uint4*)&Kp[(size_t)(m1 + sr + 32) * DH + sc * 8];
            rv0 = *(const uint4*)&Vp[(size_t)sr * NN + m1 + sc * 8];
            rv1 = *(const uint4*)&Vp[(size_t)(sr + 32) * NN + m1 + sc * 8];
        }
        // ---- S^T = K·Q^T, P = exp2(S) immediately (no max, no rescale) ----
#pragma unroll
        for (int nt = 0; nt < 4; ++nt) {
            const int rb = (nt * 16 + lo) * 64;
            bf16x8 a0 = *(const bf16x8*)&Ks[rb + SWZC(lo, quad)];
            bf16x8 a1 = *(const bf16x8*)&Ks[rb + SWZC(lo, quad + 4)];
            const int pcol = (((nt * 2 + (quad >> 1)) ^ key) << 3) + (quad & 1) * 4;
#pragma unroll
            for (int qt = 0; qt < 2; ++qt) {
                f32x4 z = (f32x4){0.f, 0.f, 0.f, 0.f};
                z = MFMA16(a0, bQ[qt][0], z);
                z = MFMA16(a1, bQ[qt][1], z);
                f32x4 p;
#pragma unroll
                for (int i = 0; i < 4; ++i) p[i] = EXP2(z[i]);
                uint2 u;
                u.x = pk2(p[0], p[1]);
                u.y = pk2(p[2], p[3]);
                *(uint2*)&Ps[(32 * w + qt * 16 + lo) * 64 + pcol] = u;
            }
        }
        asm volatile("s_waitcnt lgkmcnt(0)" ::: "memory");   // wave-private P write->read
        bf16x8 pb[2][2];
#pragma unroll
        for (int qt = 0; qt < 2; ++qt) {
            const int prow = (32 * w + qt * 16 + lo) * 64;
            pb[qt][0] = *(const bf16x8*)&Ps[prow + SWZC(lo, quad)];
            pb[qt][1] = *(const bf16x8*)&Ps[prow + SWZC(lo, quad + 4)];
        }
        // ---- O^T += V^T·P^T (+ ones-row for l) ----
#pragma unroll
        for (int ct = 0; ct < 4; ++ct) {
            const int rb = (ct * 16 + lo) * 64;
            bf16x8 a0 = *(const bf16x8*)&Vs[rb + SWZC(lo, quad)];
            bf16x8 a1 = *(const bf16x8*)&Vs[rb + SWZC(lo, quad + 4)];
#pragma unroll
            for (int qt = 0; qt < 2; ++qt) {
                O[ct][qt] = MFMA16(a0, pb[qt][0], O[ct][qt]);
                O[ct][qt] = MFMA16(a1, pb[qt][1], O[ct][qt]);
            }
        }
#pragma unroll
        for (int qt = 0; qt < 2; ++qt) {
            lacc[qt] = MFMA16(aOnes, pb[qt][0], lacc[qt]);
            lacc[qt] = MFMA16(aOnes, pb[qt][1], lacc[qt]);
        }
    }
    // ---- Y store via Ps bounce (wave-private rows -> write needs no barrier) ----
#pragma unroll
    for (int qt = 0; qt < 2; ++qt) {
        const float lv = __shfl(lacc[qt][0], lo);    // l at (quad 0, reg 0), col = lo
        const float inv = 1.f / lv;
        const int qr = 32 * w + qt * 16 + lo;
#pragma unroll
        for (int ct = 0; ct < 4; ++ct) {
            const int p = ct * 4 + quad;             // c>>2, 16 groups/row
            uint2 u;
            u.x = pk2(O[ct][qt][0] * inv, O[ct][qt][1] * inv);
            u.y = pk2(O[ct][qt][2] * inv, O[ct][qt][3] * inv);
            *(uint2*)&Ps[qr * 64 + ((p ^ (qr & 15)) << 2)] = u;
        }
    }
    __syncthreads();
    {
        const int qr = t & 127, e = t >> 7;          // row q, 64B-half
        uint2 gbuf[8];
#pragma unroll
        for (int j = 0; j < 8; ++j) {
            const int p = e * 8 + j;
            gbuf[j] = *(const uint2*)&Ps[qr * 64 + ((p ^ (qr & 15)) << 2)];
        }
        unsigned short* yrow = Yb + ((size_t)(b * NN) + q0 + qr) * HIDDEN + h * DH + e * 32;
#pragma unroll
        for (int j = 0; j < 4; ++j) *(uint4*)&yrow[j * 8] = *(uint4*)&gbuf[j * 2];
    }
}

// ---------------- Kernel C: out projection; LDS-bounced coalesced fp32 stores ----------------
__global__ __launch_bounds__(256, 4) void out_gemm(const unsigned short* __restrict__ Yb,
                                                   const unsigned short* __restrict__ Wob,
                                                   const float* __restrict__ bias,
                                                   float* __restrict__ out) {
    __shared__ unsigned short Ys[128 * 64], Wos[64 * 64];
    const int bn0 = blockIdx.x * 128, o0 = blockIdx.y * 64;
    const int t = threadIdx.x, l = t & 63, w = t >> 6, lo = l & 15, quad = l >> 4;
    const int wn = w * 32;
    const int sr = t >> 1, scb = (t & 1) * 4;
    const int sr2 = t >> 2, scb2 = (t & 3) * 2;
    f32x4 acc[2][4];
#pragma unroll
    for (int i = 0; i < 2; ++i)
#pragma unroll
        for (int j = 0; j < 4; ++j) acc[i][j] = (f32x4){0.f, 0.f, 0.f, 0.f};

    for (int kc = 0; kc < HIDDEN; kc += 64) {
        __syncthreads();
#pragma unroll
        for (int j = 0; j < 4; ++j) {
            const int ch = scb + j;
            *(uint4*)&Ys[sr * 64 + SWZC(sr, ch)] =
                *(const uint4*)&Yb[(size_t)(bn0 + sr) * HIDDEN + kc + ch * 8];
        }
#pragma unroll
        for (int j = 0; j < 2; ++j) {
            const int ch = scb2 + j;
            *(uint4*)&Wos[sr2 * 64 + SWZC(sr2, ch)] =
                *(const uint4*)&Wob[(size_t)(o0 + sr2) * HIDDEN + kc + ch * 8];
        }
        __syncthreads();
#pragma unroll
        for (int kk = 0; kk < 2; ++kk) {
            const int swz = SWZC(lo, kk * 4 + quad);
            bf16x8 bv[4];
#pragma unroll
            for (int ot = 0; ot < 4; ++ot) bv[ot] = *(const bf16x8*)&Wos[(ot * 16 + lo) * 64 + swz];
#pragma unroll
            for (int mt = 0; mt < 2; ++mt) {
                bf16x8 av = *(const bf16x8*)&Ys[(wn + mt * 16 + lo) * 64 + swz];
#pragma unroll
                for (int ot = 0; ot < 4; ++ot) acc[mt][ot] = MFMA16(av, bv[ot], acc[mt][ot]);
            }
        }
    }
    // ---- epilogue: two 32-o passes through a 16 KB fp32 bounce ----
    const int bb = bn0 >> 11, n_glob = bn0 & 2047;
    float* LF = (float*)Ys;                        // 4096 floats
#pragma unroll
    for (int pass = 0; pass < 2; ++pass) {
        __syncthreads();                           // pass 0: frag reads done; pass 1: prior reads done
#pragma unroll
        for (int ot2 = 0; ot2 < 2; ++ot2) {
            const int ot = pass * 2 + ot2;
            const int oL = ot2 * 16 + lo;          // 0..31
            const float bv = bias[o0 + ot * 16 + lo];
#pragma unroll
            for (int mt = 0; mt < 2; ++mt) {
                const int g = (wn >> 2) + mt * 4 + quad;   // n'>>2 in 0..31
                *(f32x4*)&LF[oL * 128 + ((g ^ (oL & 31)) << 2)] = acc[mt][ot] + bv;
            }
        }
        __syncthreads();
        const int oL = t >> 3, seg = t & 7;        // 32 rows x 8 segments of 64B
        f32x4 fb[4];
#pragma unroll
        for (int j = 0; j < 4; ++j) {
            const int g = seg * 4 + j;
            fb[j] = *(const f32x4*)&LF[oL * 128 + ((g ^ (oL & 31)) << 2)];
        }
        float* orow = out + ((size_t)(bb * CDIM + o0 + pass * 32 + oL)) * NN + n_glob + seg * 16;
#pragma unroll
        for (int j = 0; j < 4; ++j) *(f32x4*)&orow[j * 4] = fb[j];
    }
}

extern "C" void kernel_launch(void* const* d_in, const int* in_sizes, int n_in,
                              void* d_out, int out_size, void* d_ws, size_t ws_size,
                              hipStream_t stream) {
    const float* x     = (const float*)d_in[0];
    const float* w_qkv = (const float*)d_in[1];
    const float* w_out = (const float*)d_in[2];
    const float* b_out = (const float*)d_in[3];
    float* out = (float*)d_out;

    unsigned short* Wqb = (unsigned short*)d_ws;
    unsigned short* Wob = Wqb + (size_t)THREEH * CDIM;
    unsigned short* Xt  = Wob + (size_t)CDIM * HIDDEN;
    unsigned short* Qb  = Xt + (size_t)BB * NN * CDIM;
    unsigned short* Kb  = Qb + (size_t)BB * HEADS * NN * DH;
    unsigned short* Vb  = Kb + (size_t)BB * HEADS * NN * DH;
    unsigned short* Yb  = Vb + (size_t)BB * HEADS * DH * NN;

    prep_all<<<544, 256, 0, stream>>>(x, w_qkv, w_out, Xt, (unsigned*)Wqb, (unsigned*)Wob);
    qkv_gemm<<<dim3(BB * NN / 128, THREEH / 128), 256, 0, stream>>>(Xt, Wqb, Qb, Kb, Vb);
    flash_attn<<<512, 256, 0, stream>>>(Qb, Kb, Vb, Yb);
    out_gemm<<<dim3(BB * NN / 128, CDIM / 64), 256, 0, stream>>>(Yb, Wob, b_out, out);
}